// Round 8
// baseline (340.072 us; speedup 1.0000x reference)
//
#include <hip/hip_runtime.h>
#include <stdint.h>

typedef __attribute__((ext_vector_type(4))) float          f32x4;
typedef __attribute__((ext_vector_type(8))) short          bf16x8;
typedef __attribute__((ext_vector_type(8))) unsigned short u16x8;
typedef __attribute__((ext_vector_type(4))) unsigned short u16x4;

static __device__ __forceinline__ unsigned short f2bf(float f){
  uint32_t u = __builtin_bit_cast(uint32_t, f);
  u += 0x7FFFu + ((u >> 16) & 1u);          // RNE
  return (unsigned short)(u >> 16);
}
static __device__ __forceinline__ float bf2f(unsigned short h){
  uint32_t u = ((uint32_t)h) << 16;
  return __builtin_bit_cast(float, u);
}

// ---------------- elementwise convert f32 -> bf16 (8/thread) ----------------
__global__ void k_cvt(const float* __restrict__ in, unsigned short* __restrict__ out, long n){
  long i = ((long)blockIdx.x * blockDim.x + threadIdx.x) * 8;
  if (i >= n) return;
  const f32x4* p = (const f32x4*)(in + i);
  f32x4 a = p[0], b = p[1];
  u16x8 o;
  #pragma unroll
  for (int j = 0; j < 4; j++){ o[j] = f2bf(a[j]); o[4+j] = f2bf(b[j]); }
  *(u16x8*)(out + i) = o;
}

// ------- strided cvt: WvB[e][hd] = bf16(w_qkv[e][1536+hd]), 768x768 ---------
__global__ void k_cvtwv(const float* __restrict__ w, unsigned short* __restrict__ out){
  const long idx = ((long)blockIdx.x * blockDim.x + threadIdx.x) * 8;
  const int e = (int)(idx / 768), hd = (int)(idx - (long)e * 768);
  const float* s = w + (long)e * 2304 + 1536 + hd;
  f32x4 a = *(const f32x4*)s, b = *(const f32x4*)(s + 4);
  u16x8 o;
  #pragma unroll
  for (int j = 0; j < 4; j++){ o[j] = f2bf(a[j]); o[4+j] = f2bf(b[j]); }
  *(u16x8*)(out + idx) = o;
}

// ---------------- tiled transpose+convert: in[R][C] f32 -> out[C][R] bf16 ----
__global__ void k_tconv(const float* __restrict__ in, unsigned short* __restrict__ out, int R, int C){
  __shared__ float tl[64][65];
  const int c0 = blockIdx.x * 64, r0 = blockIdx.y * 64;
  const int t = threadIdx.x;
  {
    const int lr = t >> 2, lc = (t & 3) * 16;
    const f32x4* s = (const f32x4*)(in + (long)(r0 + lr) * C + c0 + lc);
    #pragma unroll
    for (int q = 0; q < 4; q++){
      f32x4 v = s[q];
      #pragma unroll
      for (int j = 0; j < 4; j++) tl[lr][lc + q*4 + j] = v[j];
    }
  }
  __syncthreads();
  {
    const int oc = t >> 2, orr = (t & 3) * 16;
    u16x8 o0, o1;
    #pragma unroll
    for (int i = 0; i < 8; i++){ o0[i] = f2bf(tl[orr + i][oc]); o1[i] = f2bf(tl[orr + 8 + i][oc]); }
    u16x8* dst = (u16x8*)(out + (long)(c0 + oc) * R + r0 + orr);
    dst[0] = o0; dst[1] = o1;
  }
}

// ===== 128x256 BK=32: A via LDS ring-3 (24KB), B direct global->regs ========
// Phase = {4 ds_read_b128 (A, split 2+2); 16 MFMA; load bq(t+1) from L2;
// stageA(t+2); vmcnt(5); bar}. LDS traffic halved vs both-operand staging;
// B (weights) is L2-resident. Compiler inserts RAW vmcnt for bq before MFMA.

static __device__ __forceinline__ void stageA(const unsigned short* __restrict__ G, int row0, int ke,
                                              char* slot, int t){
  const int r  = t >> 2;
  const int ko = (t & 3) ^ ((r ^ (r >> 2)) & 3);
  const char* src = (const char*)(G + (long)(row0 + r) * 768 + ke + ko * 8);
  char* dst = slot + (t & 0x1C0) * 16;                       // wave-uniform base
  __builtin_amdgcn_global_load_lds((const __attribute__((address_space(1))) unsigned int*)src,
                                   (__attribute__((address_space(3))) unsigned int*)dst, 16, 0, 0);
}

static __device__ __forceinline__ bf16x8 ldfrag(const char* slot, int row, int ko){
  const int k2 = (ko ^ (row ^ (row >> 2))) & 3;
  return *(const bf16x8*)(slot + row*64 + k2*16);
}

#define MFMA_(a,b,c) __builtin_amdgcn_mfma_f32_16x16x32_bf16(a,b,c,0,0,0)

#define LDB4(KE)                                                               \
    bqv[0] = *(const bf16x8*)(bbase + (KE));                                   \
    bqv[1] = *(const bf16x8*)(bbase + 12288 + (KE));                           \
    bqv[2] = *(const bf16x8*)(bbase + 24576 + (KE));                           \
    bqv[3] = *(const bf16x8*)(bbase + 36864 + (KE));

#define POSTN(KE1, SLOT2, KE2)                                                 \
    LDB4(KE1)                                                                  \
    stageA(A, m0, (KE2), (SLOT2), t);                                          \
    __builtin_amdgcn_sched_barrier(0);                                         \
    asm volatile("s_waitcnt vmcnt(5)" ::: "memory");                           \
    __builtin_amdgcn_s_barrier();

#define POSTT                                                                  \
    LDB4(736)                                                                  \
    __builtin_amdgcn_sched_barrier(0);                                         \
    asm volatile("s_waitcnt vmcnt(4)" ::: "memory");                           \
    __builtin_amdgcn_s_barrier();

#define PH(CUR, POST) do {                                                     \
    {                                                                          \
      bf16x8 a0 = ldfrag(sA[CUR], wm64 +  0 + arow, ko);                       \
      bf16x8 a1 = ldfrag(sA[CUR], wm64 + 16 + arow, ko);                       \
      __builtin_amdgcn_s_setprio(1);                                           \
      _Pragma("unroll")                                                        \
      for (int ni = 0; ni < 4; ni++) acc[0][ni] = MFMA_(a0, bqv[ni], acc[0][ni]); \
      _Pragma("unroll")                                                        \
      for (int ni = 0; ni < 4; ni++) acc[1][ni] = MFMA_(a1, bqv[ni], acc[1][ni]); \
    }                                                                          \
    {                                                                          \
      bf16x8 a2 = ldfrag(sA[CUR], wm64 + 32 + arow, ko);                       \
      bf16x8 a3 = ldfrag(sA[CUR], wm64 + 48 + arow, ko);                       \
      _Pragma("unroll")                                                        \
      for (int ni = 0; ni < 4; ni++) acc[2][ni] = MFMA_(a2, bqv[ni], acc[2][ni]); \
      _Pragma("unroll")                                                        \
      for (int ni = 0; ni < 4; ni++) acc[3][ni] = MFMA_(a3, bqv[ni], acc[3][ni]); \
      __builtin_amdgcn_s_setprio(0);                                           \
    }                                                                          \
    POST                                                                       \
  } while(0)

// MODE 0: A=x_bf[32768][768], BT=WT[1536 q||k][768] -> QT/KT (transposed) + nrmp
// MODE 1: A=x_bf[32768][768], BT=WcombT[8][768][768] (batched) -> OUTF + bias
template<int MODE>
__global__ __launch_bounds__(512, 4)
void k_gemm4(const unsigned short* __restrict__ A, const unsigned short* __restrict__ BT,
             unsigned short* __restrict__ QT, unsigned short* __restrict__ KT,
             float* __restrict__ OUTF, const float* __restrict__ bias,
             float* __restrict__ nrmp)
{
  __shared__ __attribute__((aligned(16))) char lds[24576];
  constexpr int NT = (MODE == 0) ? 6 : 3;
  constexpr int NWG = 256 * NT;
  const int o  = blockIdx.x;
  const int wg = (o & 7) * (NWG >> 3) + (o >> 3);          // bijective XCD swizzle
  const int jt = wg % NT, mt = wg / NT;
  const int m0 = mt * 128, j0 = jt * 256;
  const int t = threadIdx.x, lane = t & 63, w = t >> 6;
  const int wm = w >> 2, wn = w & 3;
  const int wm64 = wm * 64;
  const int arow = lane & 15, ko = lane >> 4;
  const unsigned short* BTb = (MODE == 1) ? BT + ((long)(m0 >> 12)) * 589824 : BT;
  const unsigned short* bbase = BTb + (long)(j0 + wn*64 + arow) * 768 + ko * 8;

  char* const sA[3] = {lds, lds + 8192, lds + 16384};

  f32x4 acc[4][4] = {};
  bf16x8 bqv[4];

  // prologue: stage A tiles 0,1; load B frags tile 0; vmcnt(5) completes A0
  stageA(A, m0, 0,  sA[0], t);
  stageA(A, m0, 32, sA[1], t);
  LDB4(0)
  __builtin_amdgcn_sched_barrier(0);
  asm volatile("s_waitcnt vmcnt(5)" ::: "memory");
  __builtin_amdgcn_s_barrier();

  #pragma unroll 1
  for (int g = 0; g < 7; ++g){                 // tiles 0..20
    const int kb = g * 96;
    PH(0, POSTN(kb + 32,  sA[2], kb + 64));
    PH(1, POSTN(kb + 64,  sA[0], kb + 96));
    PH(2, POSTN(kb + 96,  sA[1], kb + 128));
  }
  // tail: tiles 21, 22, 23
  PH(0, POSTN(704, sA[2], 736));
  PH(1, POSTT);
  PH(2, {});

  if (MODE == 0){
    const int b = m0 >> 12;
    const int nb = (m0 & 4095) + wm*64 + (lane >> 4)*4;
    #pragma unroll
    for (int mi = 0; mi < 4; mi++){
      #pragma unroll
      for (int ni = 0; ni < 4; ni++){
        const int jc = j0 + wn*64 + ni*16 + (lane & 15);
        const int s  = (jc >= 768);
        const int jl = jc - s * 768;
        const int h  = jl / 48;
        const int c  = jl - h * 48;
        unsigned short* dst = (s ? KT : QT) + (((long)(b*16 + h) * 48 + c) << 12) + nb + mi*16;
        u16x4 pk;
        #pragma unroll
        for (int r = 0; r < 4; r++) pk[r] = f2bf(acc[mi][ni][r]);
        *(u16x4*)dst = pk;
      }
    }
    // per-(row, 64-chunk) sum-of-squares partials (fp32, pre-bf16)
    const int chunk = ((m0 & 4095) >> 6) + wm;   // 64 chunks of 64 per batch-row
    #pragma unroll
    for (int ni = 0; ni < 4; ni++){
      float ss = 0.f;
      #pragma unroll
      for (int mi = 0; mi < 4; mi++)
        #pragma unroll
        for (int r = 0; r < 4; r++) ss += acc[mi][ni][r] * acc[mi][ni][r];
      ss += __shfl_xor(ss, 16);
      ss += __shfl_xor(ss, 32);
      if (lane < 16){
        const int jc = j0 + wn*64 + ni*16 + lane;
        const int s  = (jc >= 768);
        const int jl = jc - s * 768;
        const int h  = jl / 48;
        const int c  = jl - h * 48;
        const int prow = s*6144 + (b*16 + h)*48 + c;
        nrmp[(long)prow*64 + chunk] = ss;
      }
    }
  } else {
    #pragma unroll
    for (int mi = 0; mi < 4; mi++){
      #pragma unroll
      for (int ni = 0; ni < 4; ni++){
        const int jc = j0 + wn*64 + ni*16 + (lane & 15);
        const float bv = bias[jc];
        const long mr = (long)m0 + wm*64 + mi*16 + (lane >> 4)*4;
        #pragma unroll
        for (int r = 0; r < 4; r++) OUTF[(mr + r) * 768 + jc] = acc[mi][ni][r] + bv;
      }
    }
  }
}

// ---------------- S partials: per (bh, ksp) 48x48 over 1024 n ---------------
__global__ __launch_bounds__(256)
void k_attn_part(const unsigned short* __restrict__ QT, const unsigned short* __restrict__ KT,
                 float* __restrict__ Spart)
{
  __shared__ float Sl[4][2304];
  const int bh = blockIdx.x, ksp = blockIdx.y;
  const int t = threadIdx.x, lane = t & 63, w = t >> 6;
  const unsigned short* qb = QT + ((long)bh * 48 << 12);
  const unsigned short* kb = KT + ((long)bh * 48 << 12);
  const int n00 = ksp * 1024 + w * 256;
  f32x4 acc[3][3] = {};
  for (int kt = 0; kt < 256; kt += 32){
    bf16x8 af[3], bfr[3];
    #pragma unroll
    for (int ci = 0; ci < 3; ci++)
      af[ci]  = *(const bf16x8*)(qb + ((long)(ci*16 + (lane & 15)) << 12) + n00 + kt + (lane >> 4) * 8);
    #pragma unroll
    for (int di = 0; di < 3; di++)
      bfr[di] = *(const bf16x8*)(kb + ((long)(di*16 + (lane & 15)) << 12) + n00 + kt + (lane >> 4) * 8);
    #pragma unroll
    for (int ci = 0; ci < 3; ci++)
      #pragma unroll
      for (int di = 0; di < 3; di++)
        acc[ci][di] = __builtin_amdgcn_mfma_f32_16x16x32_bf16(af[ci], bfr[di], acc[ci][di], 0, 0, 0);
  }
  #pragma unroll
  for (int ci = 0; ci < 3; ci++)
    #pragma unroll
    for (int di = 0; di < 3; di++)
      #pragma unroll
      for (int r = 0; r < 4; r++)
        Sl[w][(ci*16 + (lane >> 4)*4 + r) * 48 + di*16 + (lane & 15)] = acc[ci][di][r];
  __syncthreads();
  float* outp = Spart + ((long)ksp * 128 + bh) * 2304;
  for (int idx = t; idx < 2304; idx += 256)
    outp[idx] = Sl[0][idx] + Sl[1][idx] + Sl[2][idx] + Sl[3][idx];
}

// --- reduce partials + norms, scale, softmax -> attnT bf16 [bh][48 d][64 c] --
__global__ void k_softmax(const float* __restrict__ Spart, const float* __restrict__ nrmp,
                          const float* __restrict__ temp, unsigned short* __restrict__ attnT)
{
  __shared__ float invq[48], invk[48];
  const int bh = blockIdx.x, h = bh & 15;
  const int c = threadIdx.x;   // 64 threads, 48 active
  if (c < 48){
    float sq = 0.f, sk = 0.f;
    const float* pq = nrmp + (long)(bh*48 + c) * 64;
    const float* pk = nrmp + (long)(6144 + bh*48 + c) * 64;
    #pragma unroll
    for (int i = 0; i < 64; i++){ sq += pq[i]; sk += pk[i]; }
    invq[c] = 1.0f / fmaxf(sqrtf(sq), 1e-12f);
    invk[c] = 1.0f / fmaxf(sqrtf(sk), 1e-12f);
  }
  __syncthreads();
  if (c < 48){
    const float scq = invq[c] * temp[h];
    float row[48];
    #pragma unroll
    for (int d = 0; d < 48; d++){
      long base = ((long)bh * 48 + c) * 48 + d;
      float v = Spart[base] + Spart[base + 128L*2304] + Spart[base + 256L*2304] + Spart[base + 384L*2304];
      row[d] = v * scq * invk[d];
    }
    float mx = -1e30f;
    #pragma unroll
    for (int d = 0; d < 48; d++) mx = fmaxf(mx, row[d]);
    float s = 0.f;
    #pragma unroll
    for (int d = 0; d < 48; d++){ row[d] = expf(row[d] - mx); s += row[d]; }
    const float inv = 1.0f / s;
    unsigned short* ob = attnT + (long)bh * 48 * 64;
    #pragma unroll
    for (int d = 0; d < 48; d++) ob[d*64 + c] = f2bf(row[d] * inv);
    u16x8 z = {};
    *(u16x8*)(ob + c*64 + 48) = z;
    *(u16x8*)(ob + c*64 + 56) = z;
  }
}

// --- WmodT[b][j][h*48+d] = sum_c attnT[bh][d][c] * WpT[j][h*48+c] (MFMA) -----
__global__ __launch_bounds__(256)
void k_wmod2(const unsigned short* __restrict__ WpT, const unsigned short* __restrict__ attnT,
             unsigned short* __restrict__ WmodT)
{
  const int j0 = blockIdx.x * 256, h = blockIdx.y, b = blockIdx.z;
  const int t = threadIdx.x, lane = t & 63, w = t >> 6;
  const unsigned short* wp = WpT + h * 48;
  const unsigned short* ab = attnT + ((long)(b*16 + h)) * 48 * 64;
  f32x4 acc[4][3] = {};
  #pragma unroll
  for (int kt = 0; kt < 64; kt += 32){
    bf16x8 bfr[3];
    #pragma unroll
    for (int ni = 0; ni < 3; ni++)
      bfr[ni] = *(const bf16x8*)(ab + (ni*16 + (lane & 15))*64 + kt + (lane >> 4)*8);
    #pragma unroll
    for (int mi = 0; mi < 4; mi++){
      const int j = j0 + w*64 + mi*16 + (lane & 15);
      bf16x8 a = *(const bf16x8*)(wp + (long)j*768 + kt + (lane >> 4)*8);
      #pragma unroll
      for (int ni = 0; ni < 3; ni++)
        acc[mi][ni] = __builtin_amdgcn_mfma_f32_16x16x32_bf16(a, bfr[ni], acc[mi][ni], 0, 0, 0);
    }
  }
  #pragma unroll
  for (int mi = 0; mi < 4; mi++)
    #pragma unroll
    for (int ni = 0; ni < 3; ni++)
      #pragma unroll
      for (int r = 0; r < 4; r++){
        const int j = j0 + w*64 + mi*16 + (lane >> 4)*4 + r;
        const int d = ni*16 + (lane & 15);
        WmodT[(long)b*589824 + (long)j*768 + h*48 + d] = f2bf(acc[mi][ni][r]);
      }
}

// --- WcombT[6144 rows=b*768+j][768 e] = WmodT[row][hd] @ WvB[e][hd] (128² tile)
__global__ __launch_bounds__(256)
void k_comb(const unsigned short* __restrict__ A, const unsigned short* __restrict__ BT,
            unsigned short* __restrict__ OUT)
{
  __shared__ unsigned short As[128 * 32];
  __shared__ unsigned short Bs[128 * 32];
  const int m0 = blockIdx.y * 128;
  const int j0 = blockIdx.x * 128;
  const int t = threadIdx.x;
  const int lane = t & 63;
  const int w = t >> 6, wm = w >> 1, wn = w & 1;

  f32x4 acc[4][4] = {};

  for (int kt = 0; kt < 768; kt += 32){
    if (kt) __syncthreads();
    #pragma unroll
    for (int i = 0; i < 2; i++){
      const char* ga = (const char*)A  + (long)(m0 + i*64 + (t >> 2)) * 1536 + kt*2 + (t & 3) * 16;
      const char* gb = (const char*)BT + (long)(j0 + i*64 + (t >> 2)) * 1536 + kt*2 + (t & 3) * 16;
      char* la = (char*)As + i*4096 + (t & 0xC0) * 16;
      char* lb = (char*)Bs + i*4096 + (t & 0xC0) * 16;
      __builtin_amdgcn_global_load_lds((const __attribute__((address_space(1))) unsigned int*)ga,
                                       (__attribute__((address_space(3))) unsigned int*)la, 16, 0, 0);
      __builtin_amdgcn_global_load_lds((const __attribute__((address_space(1))) unsigned int*)gb,
                                       (__attribute__((address_space(3))) unsigned int*)lb, 16, 0, 0);
    }
    __syncthreads();
    bf16x8 af[4], bfr[4];
    #pragma unroll
    for (int mi = 0; mi < 4; mi++)
      af[mi]  = *(const bf16x8*)&As[(wm*64 + mi*16 + (lane & 15)) * 32 + (lane >> 4) * 8];
    #pragma unroll
    for (int ni = 0; ni < 4; ni++)
      bfr[ni] = *(const bf16x8*)&Bs[(wn*64 + ni*16 + (lane & 15)) * 32 + (lane >> 4) * 8];
    #pragma unroll
    for (int mi = 0; mi < 4; mi++)
      #pragma unroll
      for (int ni = 0; ni < 4; ni++)
        acc[mi][ni] = __builtin_amdgcn_mfma_f32_16x16x32_bf16(af[mi], bfr[ni], acc[mi][ni], 0, 0, 0);
  }

  #pragma unroll
  for (int mi = 0; mi < 4; mi++)
    #pragma unroll
    for (int ni = 0; ni < 4; ni++){
      const int jc = j0 + wn*64 + ni*16 + (lane & 15);
      const long mr = (long)m0 + wm*64 + mi*16 + (lane >> 4) * 4;
      #pragma unroll
      for (int r = 0; r < 4; r++) OUT[(mr + r) * 768 + jc] = f2bf(acc[mi][ni][r]);
    }
}

extern "C" void kernel_launch(void* const* d_in, const int* in_sizes, int n_in,
                              void* d_out, int out_size, void* d_ws, size_t ws_size,
                              hipStream_t stream)
{
  (void)in_sizes; (void)n_in; (void)out_size; (void)ws_size;
  const float* x      = (const float*)d_in[0];
  const float* w_qkv  = (const float*)d_in[1];
  const float* temp   = (const float*)d_in[2];
  const float* w_proj = (const float*)d_in[3];
  const float* b_proj = (const float*)d_in[4];
  float* outF = (float*)d_out;

  char* ws = (char*)d_ws;
  size_t off = 0;
  auto alloc = [&](size_t bytes)->char*{ char* p = ws + off; off += (bytes + 255) & ~(size_t)255; return p; };

  unsigned short* x_bf  = (unsigned short*)alloc(50331648);           // [32768][768] bf16
  unsigned short* WT    = (unsigned short*)alloc(3538944);            // [2304][768] bf16 (rows 0..1535 used)
  unsigned short* WpT   = (unsigned short*)alloc(1179648);            // [768][768] bf16
  unsigned short* WvB   = (unsigned short*)alloc(1179648);            // [768 e][768 hd] bf16
  unsigned short* QT    = (unsigned short*)alloc(100663296);          // QT||KT [6144][4096] bf16 each
  unsigned short* KT    = QT + (long)6144 * 4096;
  float* nrmp           = (float*)alloc(12288L * 64 * 4);             // [12288 rows][64 chunks] f32
  float* Spart          = (float*)alloc(4L * 128 * 2304 * 4);         // [4][128][48][48] f32
  unsigned short* attnT = (unsigned short*)alloc(128L * 48 * 64 * 2); // [128][48 d][64 c] bf16
  unsigned short* WmodT = (unsigned short*)alloc(9437184);            // [8][768 j][768 hd] bf16
  unsigned short* WcombT= (unsigned short*)alloc(9437184);            // [8][768 j][768 e] bf16

  k_cvt<<<12288, 256, 0, stream>>>(x, x_bf, 25165824L);
  k_tconv<<<dim3(36, 12), 256, 0, stream>>>(w_qkv, WT, 768, 2304);
  k_tconv<<<dim3(12, 12), 256, 0, stream>>>(w_proj, WpT, 768, 768);
  k_cvtwv<<<288, 256, 0, stream>>>(w_qkv, WvB);
  k_gemm4<0><<<1536, 512, 0, stream>>>(x_bf, WT, QT, KT, nullptr, nullptr, nrmp);
  k_attn_part<<<dim3(128, 4), 256, 0, stream>>>(QT, KT, Spart);
  k_softmax<<<128, 64, 0, stream>>>(Spart, nrmp, temp, attnT);
  k_wmod2<<<dim3(3, 16, 8), 256, 0, stream>>>(WpT, attnT, WmodT);
  k_comb<<<dim3(6, 48), 256, 0, stream>>>(WmodT, WvB, WcombT);
  k_gemm4<1><<<768, 512, 0, stream>>>(x_bf, WcombT, nullptr, nullptr, outF, b_proj, nullptr);
}

// Round 9
// 245.519 us; speedup vs baseline: 1.3851x; 1.3851x over previous
//
#include <hip/hip_runtime.h>
#include <stdint.h>

typedef __attribute__((ext_vector_type(4))) float          f32x4;
typedef __attribute__((ext_vector_type(8))) short          bf16x8;
typedef __attribute__((ext_vector_type(8))) unsigned short u16x8;
typedef __attribute__((ext_vector_type(4))) unsigned short u16x4;

static __device__ __forceinline__ unsigned short f2bf(float f){
  uint32_t u = __builtin_bit_cast(uint32_t, f);
  u += 0x7FFFu + ((u >> 16) & 1u);          // RNE
  return (unsigned short)(u >> 16);
}
static __device__ __forceinline__ float bf2f(unsigned short h){
  uint32_t u = ((uint32_t)h) << 16;
  return __builtin_bit_cast(float, u);
}

// ---------------- elementwise convert f32 -> bf16 (8/thread) ----------------
__global__ void k_cvt(const float* __restrict__ in, unsigned short* __restrict__ out, long n){
  long i = ((long)blockIdx.x * blockDim.x + threadIdx.x) * 8;
  if (i >= n) return;
  const f32x4* p = (const f32x4*)(in + i);
  f32x4 a = p[0], b = p[1];
  u16x8 o;
  #pragma unroll
  for (int j = 0; j < 4; j++){ o[j] = f2bf(a[j]); o[4+j] = f2bf(b[j]); }
  *(u16x8*)(out + i) = o;
}

// ------- strided cvt: WvB[e][hd] = bf16(w_qkv[e][1536+hd]), 768x768 ---------
__global__ void k_cvtwv(const float* __restrict__ w, unsigned short* __restrict__ out){
  const long idx = ((long)blockIdx.x * blockDim.x + threadIdx.x) * 8;
  const int e = (int)(idx / 768), hd = (int)(idx - (long)e * 768);
  const float* s = w + (long)e * 2304 + 1536 + hd;
  f32x4 a = *(const f32x4*)s, b = *(const f32x4*)(s + 4);
  u16x8 o;
  #pragma unroll
  for (int j = 0; j < 4; j++){ o[j] = f2bf(a[j]); o[4+j] = f2bf(b[j]); }
  *(u16x8*)(out + idx) = o;
}

// ---------------- tiled transpose+convert: in[R][C] f32 -> out[C][R] bf16 ----
__global__ void k_tconv(const float* __restrict__ in, unsigned short* __restrict__ out, int R, int C){
  __shared__ float tl[64][65];
  const int c0 = blockIdx.x * 64, r0 = blockIdx.y * 64;
  const int t = threadIdx.x;
  {
    const int lr = t >> 2, lc = (t & 3) * 16;
    const f32x4* s = (const f32x4*)(in + (long)(r0 + lr) * C + c0 + lc);
    #pragma unroll
    for (int q = 0; q < 4; q++){
      f32x4 v = s[q];
      #pragma unroll
      for (int j = 0; j < 4; j++) tl[lr][lc + q*4 + j] = v[j];
    }
  }
  __syncthreads();
  {
    const int oc = t >> 2, orr = (t & 3) * 16;
    u16x8 o0, o1;
    #pragma unroll
    for (int i = 0; i < 8; i++){ o0[i] = f2bf(tl[orr + i][oc]); o1[i] = f2bf(tl[orr + 8 + i][oc]); }
    u16x8* dst = (u16x8*)(out + (long)(c0 + oc) * R + r0 + orr);
    dst[0] = o0; dst[1] = o1;
  }
}

// ---- tconv for WTr: w_qkv cols 0..1535 -> WTr[perm(col)][768], head-pair layout
// head h, c, q/k -> row (h>>1)*192 + (h&1)*96 + isK*48 + c
static __device__ __forceinline__ int mapW(int j){
  const int isK = (j >= 768);
  const int jj = j - isK * 768;
  const int h = jj / 48, c = jj - h * 48;
  return (h >> 1) * 192 + (h & 1) * 96 + isK * 48 + c;
}
__global__ void k_tconvQK(const float* __restrict__ in, unsigned short* __restrict__ out){
  __shared__ float tl[64][65];
  const int c0 = blockIdx.x * 64, r0 = blockIdx.y * 64;   // cols 0..1535, rows 0..767
  const int t = threadIdx.x;
  {
    const int lr = t >> 2, lc = (t & 3) * 16;
    const f32x4* s = (const f32x4*)(in + (long)(r0 + lr) * 2304 + c0 + lc);
    #pragma unroll
    for (int q = 0; q < 4; q++){
      f32x4 v = s[q];
      #pragma unroll
      for (int j = 0; j < 4; j++) tl[lr][lc + q*4 + j] = v[j];
    }
  }
  __syncthreads();
  {
    const int oc = t >> 2, orr = (t & 3) * 16;
    u16x8 o0, o1;
    #pragma unroll
    for (int i = 0; i < 8; i++){ o0[i] = f2bf(tl[orr + i][oc]); o1[i] = f2bf(tl[orr + 8 + i][oc]); }
    u16x8* dst = (u16x8*)(out + (long)mapW(c0 + oc) * 768 + r0 + orr);
    dst[0] = o0; dst[1] = o1;
  }
}

// ===================== shared GEMM machinery (BK=32, ring-3) ================
// Swizzle: LDS chunk c of row r holds global k-chunk (c ^ s(r)), s(r)=(r>>1)&3.
// Bank math: read banks (16*(r&1) + 4*((r>>1)&3 ^ ko)) -> exactly 2-way = free.

static __device__ __forceinline__ bf16x8 ldfrag(const char* slot, int row, int ko){
  const int k2 = (ko ^ (row >> 1)) & 3;
  return *(const bf16x8*)(slot + row*64 + k2*16);
}

// 512-thread stagers (rows 128 / 256)
static __device__ __forceinline__ void stageA512(const unsigned short* __restrict__ G, int row0, int ke,
                                                 char* slot, int t){
  const int r  = t >> 2;
  const int ko = (t & 3) ^ ((r >> 1) & 3);
  const char* src = (const char*)(G + (long)(row0 + r) * 768 + ke + ko * 8);
  char* dst = slot + (t & 0x1C0) * 16;
  __builtin_amdgcn_global_load_lds((const __attribute__((address_space(1))) unsigned int*)src,
                                   (__attribute__((address_space(3))) unsigned int*)dst, 16, 0, 0);
}
static __device__ __forceinline__ void stageB512(const unsigned short* __restrict__ G, int row0, int ke,
                                                 char* slot, int t){
  #pragma unroll
  for (int l = 0; l < 2; l++){
    const int r  = l*128 + (t >> 2);
    const int ko = (t & 3) ^ ((r >> 1) & 3);
    const char* src = (const char*)(G + (long)(row0 + r) * 768 + ke + ko * 8);
    char* dst = slot + l*8192 + (t & 0x1C0) * 16;
    __builtin_amdgcn_global_load_lds((const __attribute__((address_space(1))) unsigned int*)src,
                                     (__attribute__((address_space(3))) unsigned int*)dst, 16, 0, 0);
  }
}

// 384-thread stagers: A 128 rows (waves 0,1 issue extra), B 192 rows (uniform 2)
static __device__ __forceinline__ void stageA384(const unsigned short* __restrict__ G, int row0, int ke,
                                                 char* slot, int t){
  {
    const int r  = t >> 2;
    const int ko = (t & 3) ^ ((r >> 1) & 3);
    const char* src = (const char*)(G + (long)(row0 + r) * 768 + ke + ko * 8);
    char* dst = slot + (t & 0x1C0) * 16;
    __builtin_amdgcn_global_load_lds((const __attribute__((address_space(1))) unsigned int*)src,
                                     (__attribute__((address_space(3))) unsigned int*)dst, 16, 0, 0);
  }
  if (t < 128){     // waves 0,1: rows 96..127
    const int r  = 96 + (t >> 2);
    const int ko = (t & 3) ^ ((r >> 1) & 3);
    const char* src = (const char*)(G + (long)(row0 + r) * 768 + ke + ko * 8);
    char* dst = slot + 6144 + (t & 0x1C0) * 16;
    __builtin_amdgcn_global_load_lds((const __attribute__((address_space(1))) unsigned int*)src,
                                     (__attribute__((address_space(3))) unsigned int*)dst, 16, 0, 0);
  }
}
static __device__ __forceinline__ void stageB384(const unsigned short* __restrict__ G, int row0, int ke,
                                                 char* slot, int t){
  #pragma unroll
  for (int l = 0; l < 2; l++){
    const int r  = l*96 + (t >> 2);
    const int ko = (t & 3) ^ ((r >> 1) & 3);
    const char* src = (const char*)(G + (long)(row0 + r) * 768 + ke + ko * 8);
    char* dst = slot + l*6144 + (t & 0x1C0) * 16;
    __builtin_amdgcn_global_load_lds((const __attribute__((address_space(1))) unsigned int*)src,
                                     (__attribute__((address_space(3))) unsigned int*)dst, 16, 0, 0);
  }
}

#define VM0 asm volatile("s_waitcnt vmcnt(0)" ::: "memory")
#define VM3 asm volatile("s_waitcnt vmcnt(3)" ::: "memory")
// per-wave-class gate for 384-thread kernel (waves 0,1 issue 4 loads/phase, others 3)
#define GATEQK { if (w < 2) asm volatile("s_waitcnt vmcnt(4)" ::: "memory");   \
                 else       asm volatile("s_waitcnt vmcnt(3)" ::: "memory"); }

#define PHASE1(CUR, STAGE_STMT, WAIT_STMT) do {                                \
    bf16x8 af[4], bq[4];                                                       \
    _Pragma("unroll")                                                          \
    for (int ni = 0; ni < 4; ni++)                                             \
      bq[ni] = ldfrag(sB[CUR], wn*64 + ni*16 + arow, ko);                      \
    _Pragma("unroll")                                                          \
    for (int mi = 0; mi < 4; mi++)                                             \
      af[mi] = ldfrag(sA[CUR], wm64 + mi*16 + arow, ko);                       \
    __builtin_amdgcn_s_barrier();                                              \
    __builtin_amdgcn_s_setprio(1);                                             \
    _Pragma("unroll")                                                          \
    for (int mi = 0; mi < 4; mi++)                                             \
      _Pragma("unroll")                                                        \
      for (int ni = 0; ni < 4; ni++)                                           \
        acc[mi][ni] = __builtin_amdgcn_mfma_f32_16x16x32_bf16(                 \
            af[mi], bq[ni], acc[mi][ni], 0, 0, 0);                             \
    __builtin_amdgcn_s_setprio(0);                                             \
    STAGE_STMT;                                                                \
    WAIT_STMT;                                                                 \
    __builtin_amdgcn_s_barrier();                                              \
  } while(0)

// ====== k_gemmQK: x_bf @ WTr^T, BM=128 BN=192 (2 heads q+k), fused S ========
// Epilogue: nrmp partials + acc->LDS bf16 tile [192][136] + per-head 48x48
// S-partial via 12 MFMA/wave -> Spart[32][128][2304].
__global__ __launch_bounds__(384, 3)
void k_gemmQK(const unsigned short* __restrict__ A, const unsigned short* __restrict__ BT,
              float* __restrict__ Spart, float* __restrict__ nrmp)
{
  __shared__ __attribute__((aligned(16))) char lds[61440];
  const int o  = blockIdx.x;
  const int wg = (o & 7) * 256 + (o >> 3);                 // bijective XCD swizzle, 2048 wgs
  const int jt = wg & 7, mt = wg >> 3;
  const int m0 = mt * 128, j0 = jt * 192;
  const int t = threadIdx.x, lane = t & 63, w = t >> 6;    // 6 waves
  const int wm = w >> 2 & 1;                               // placeholder, fixed below
  const int wmr = (w < 3) ? 0 : 1;                         // wm: waves 0-2 -> 0, 3-5 -> 1
  const int wn  = (w < 3) ? w : w - 3;                     // wn in [0,3)
  const int wm64 = wmr * 64;
  const int arow = lane & 15, ko = lane >> 4;
  (void)wm;

  char* const sA[3] = {lds,          lds + 8192,          lds + 16384};
  char* const sB[3] = {lds + 24576,  lds + 24576 + 12288, lds + 24576 + 24576};

  f32x4 acc[4][4] = {};

  stageA384(A, m0, 0,  sA[0], t);  stageB384(BT, j0, 0,  sB[0], t);
  stageA384(A, m0, 32, sA[1], t);  stageB384(BT, j0, 32, sB[1], t);
  GATEQK;
  __builtin_amdgcn_s_barrier();

  #pragma unroll 1
  for (int g = 0; g < 7; ++g){                 // tiles 0..20
    const int kb = g * 96;
    PHASE1(0, { stageA384(A, m0, kb+64,  sA[2], t); stageB384(BT, j0, kb+64,  sB[2], t); }, GATEQK);
    PHASE1(1, { stageA384(A, m0, kb+96,  sA[0], t); stageB384(BT, j0, kb+96,  sB[0], t); }, GATEQK);
    PHASE1(2, { stageA384(A, m0, kb+128, sA[1], t); stageB384(BT, j0, kb+128, sB[1], t); }, GATEQK);
  }
  PHASE1(0, { stageA384(A, m0, 736, sA[2], t); stageB384(BT, j0, 736, sB[2], t); }, GATEQK);
  PHASE1(1, { ; }, VM0);
  PHASE1(2, { ; }, ;);

  // ---------------- epilogue ----------------
  const int b = m0 >> 12;
  // (1) nrmp: per-(row, 64-chunk of 64 n) sum-of-squares, fp32 pre-bf16
  const int chunk = ((m0 & 4095) >> 6) + wmr;
  #pragma unroll
  for (int ni = 0; ni < 4; ni++){
    float ss = 0.f;
    #pragma unroll
    for (int mi = 0; mi < 4; mi++)
      #pragma unroll
      for (int r = 0; r < 4; r++) ss += acc[mi][ni][r] * acc[mi][ni][r];
    ss += __shfl_xor(ss, 16);
    ss += __shfl_xor(ss, 32);
    if (lane < 16){
      const int jr = wn*64 + ni*16 + lane;     // [0,192)
      const int hl = jr / 96, rem = jr - hl*96;
      const int isK = (rem >= 48), c = rem - isK*48;
      const int prow = isK*6144 + (b*16 + jt*2 + hl)*48 + c;
      nrmp[(long)prow*64 + chunk] = ss;
    }
  }
  // (2) acc -> LDS bf16 tile T[192 j][136 n] (272B rows, 16B-aligned, 2-way banks)
  __syncthreads();     // ring buffers dead; reuse lds as T
  #pragma unroll
  for (int mi = 0; mi < 4; mi++){
    #pragma unroll
    for (int ni = 0; ni < 4; ni++){
      const int j = wn*64 + ni*16 + (lane & 15);
      const int n = wm64 + mi*16 + (lane >> 4)*4;
      u16x4 pk;
      #pragma unroll
      for (int r = 0; r < 4; r++) pk[r] = f2bf(acc[mi][ni][r]);
      *(u16x4*)(lds + (long)j*272 + n*2) = pk;
    }
  }
  __syncthreads();
  // (3) S-partial: wave w -> head-local hl=w/3, c-row band ci=w%3
  {
    const int hl = (w < 3) ? 0 : 1;
    const int ci = (w < 3) ? w : w - 3;
    f32x4 accs[3] = {};
    #pragma unroll
    for (int kt = 0; kt < 128; kt += 32){
      const bf16x8 aq = *(const bf16x8*)(lds + (long)(hl*96 + ci*16 + (lane & 15))*272
                                             + (kt + (lane >> 4)*8)*2);
      #pragma unroll
      for (int di = 0; di < 3; di++){
        const bf16x8 bk = *(const bf16x8*)(lds + (long)(hl*96 + 48 + di*16 + (lane & 15))*272
                                               + (kt + (lane >> 4)*8)*2);
        accs[di] = __builtin_amdgcn_mfma_f32_16x16x32_bf16(aq, bk, accs[di], 0, 0, 0);
      }
    }
    const int ksp = (m0 & 4095) >> 7;
    float* Sb = Spart + ((long)ksp*128 + b*16 + jt*2 + hl) * 2304;
    #pragma unroll
    for (int di = 0; di < 3; di++)
      #pragma unroll
      for (int r = 0; r < 4; r++){
        const int c = ci*16 + (lane >> 4)*4 + r;
        const int d = di*16 + (lane & 15);
        Sb[c*48 + d] = accs[di][r];
      }
  }
}

// ====== k_gemmP: x_bf @ WcombT_b (batched), BM=128 BN=256 (r7 structure) ====
__global__ __launch_bounds__(512, 4)
void k_gemmP(const unsigned short* __restrict__ A, const unsigned short* __restrict__ BT,
             float* __restrict__ OUTF, const float* __restrict__ bias)
{
  __shared__ __attribute__((aligned(16))) char lds[73728];
  const int o  = blockIdx.x;
  const int wg = (o & 7) * 96 + (o >> 3);                  // 768 wgs
  const int jt = wg % 3, mt = wg / 3;
  const int m0 = mt * 128, j0 = jt * 256;
  const int t = threadIdx.x, lane = t & 63, w = t >> 6;
  const int wm = w >> 2, wn = w & 3;
  const int wm64 = wm * 64;
  const int arow = lane & 15, ko = lane >> 4;
  const unsigned short* BTb = BT + ((long)(m0 >> 12)) * 589824;

  char* const sA[3] = {lds,          lds + 8192,          lds + 16384};
  char* const sB[3] = {lds + 24576,  lds + 24576 + 16384, lds + 24576 + 32768};

  f32x4 acc[4][4] = {};

  stageA512(A, m0, 0,  sA[0], t);  stageB512(BTb, j0, 0,  sB[0], t);
  stageA512(A, m0, 32, sA[1], t);  stageB512(BTb, j0, 32, sB[1], t);
  VM3;
  __builtin_amdgcn_s_barrier();

  #pragma unroll 1
  for (int g = 0; g < 7; ++g){
    const int kb = g * 96;
    PHASE1(0, { stageA512(A, m0, kb+64,  sA[2], t); stageB512(BTb, j0, kb+64,  sB[2], t); }, VM3);
    PHASE1(1, { stageA512(A, m0, kb+96,  sA[0], t); stageB512(BTb, j0, kb+96,  sB[0], t); }, VM3);
    PHASE1(2, { stageA512(A, m0, kb+128, sA[1], t); stageB512(BTb, j0, kb+128, sB[1], t); }, VM3);
  }
  PHASE1(0, { stageA512(A, m0, 736, sA[2], t); stageB512(BTb, j0, 736, sB[2], t); }, VM3);
  PHASE1(1, { ; }, VM0);
  PHASE1(2, { ; }, ;);

  #pragma unroll
  for (int mi = 0; mi < 4; mi++){
    #pragma unroll
    for (int ni = 0; ni < 4; ni++){
      const int jc = j0 + wn*64 + ni*16 + (lane & 15);
      const float bv = bias[jc];
      const long mr = (long)m0 + wm64 + mi*16 + (lane >> 4)*4;
      #pragma unroll
      for (int r = 0; r < 4; r++) OUTF[(mr + r) * 768 + jc] = acc[mi][ni][r] + bv;
    }
  }
}

// --- reduce 32 S-partials + norms, scale, softmax -> attnT bf16 [bh][48][64] -
__global__ void k_softmax(const float* __restrict__ Spart, const float* __restrict__ nrmp,
                          const float* __restrict__ temp, unsigned short* __restrict__ attnT)
{
  __shared__ float Ss[2304];
  __shared__ float invq[48], invk[48];
  const int bh = blockIdx.x, h = bh & 15;
  const int t = threadIdx.x;   // 64
  f32x4 a0[9];
  #pragma unroll
  for (int v = 0; v < 9; v++) a0[v] = f32x4{0.f,0.f,0.f,0.f};
  for (int p = 0; p < 32; p++){
    const f32x4* src = (const f32x4*)(Spart + ((long)p*128 + bh)*2304);
    #pragma unroll
    for (int v = 0; v < 9; v++) a0[v] += src[v*64 + t];
  }
  #pragma unroll
  for (int v = 0; v < 9; v++) *(f32x4*)(Ss + (v*64 + t)*4) = a0[v];
  if (t < 48){
    float sq = 0.f, sk = 0.f;
    const float* pq = nrmp + (long)(bh*48 + t) * 64;
    const float* pk = nrmp + (long)(6144 + bh*48 + t) * 64;
    #pragma unroll
    for (int i = 0; i < 64; i++){ sq += pq[i]; sk += pk[i]; }
    invq[t] = 1.0f / fmaxf(sqrtf(sq), 1e-12f);
    invk[t] = 1.0f / fmaxf(sqrtf(sk), 1e-12f);
  }
  __syncthreads();
  if (t < 48){
    const int c = t;
    const float scq = invq[c] * temp[h];
    float row[48];
    #pragma unroll
    for (int d = 0; d < 48; d++) row[d] = Ss[c*48 + d] * scq * invk[d];
    float mx = -1e30f;
    #pragma unroll
    for (int d = 0; d < 48; d++) mx = fmaxf(mx, row[d]);
    float s = 0.f;
    #pragma unroll
    for (int d = 0; d < 48; d++){ row[d] = expf(row[d] - mx); s += row[d]; }
    const float inv = 1.0f / s;
    unsigned short* ob = attnT + (long)bh * 48 * 64;
    #pragma unroll
    for (int d = 0; d < 48; d++) ob[d*64 + c] = f2bf(row[d] * inv);
    u16x8 z = {};
    *(u16x8*)(ob + c*64 + 48) = z;
    *(u16x8*)(ob + c*64 + 56) = z;
  }
}

// --- WmodT[b][j][h*48+d] = sum_c attnT[bh][d][c] * WpT[j][h*48+c] (MFMA) -----
__global__ __launch_bounds__(256)
void k_wmod2(const unsigned short* __restrict__ WpT, const unsigned short* __restrict__ attnT,
             unsigned short* __restrict__ WmodT)
{
  const int j0 = blockIdx.x * 256, h = blockIdx.y, b = blockIdx.z;
  const int t = threadIdx.x, lane = t & 63, w = t >> 6;
  const unsigned short* wp = WpT + h * 48;
  const unsigned short* ab = attnT + ((long)(b*16 + h)) * 48 * 64;
  f32x4 acc[4][3] = {};
  #pragma unroll
  for (int kt = 0; kt < 64; kt += 32){
    bf16x8 bfr[3];
    #pragma unroll
    for (int ni = 0; ni < 3; ni++)
      bfr[ni] = *(const bf16x8*)(ab + (ni*16 + (lane & 15))*64 + kt + (lane >> 4)*8);
    #pragma unroll
    for (int mi = 0; mi < 4; mi++){
      const int j = j0 + w*64 + mi*16 + (lane & 15);
      bf16x8 a = *(const bf16x8*)(wp + (long)j*768 + kt + (lane >> 4)*8);
      #pragma unroll
      for (int ni = 0; ni < 3; ni++)
        acc[mi][ni] = __builtin_amdgcn_mfma_f32_16x16x32_bf16(a, bfr[ni], acc[mi][ni], 0, 0, 0);
    }
  }
  #pragma unroll
  for (int mi = 0; mi < 4; mi++)
    #pragma unroll
    for (int ni = 0; ni < 3; ni++)
      #pragma unroll
      for (int r = 0; r < 4; r++){
        const int j = j0 + w*64 + mi*16 + (lane >> 4)*4 + r;
        const int d = ni*16 + (lane & 15);
        WmodT[(long)b*589824 + (long)j*768 + h*48 + d] = f2bf(acc[mi][ni][r]);
      }
}

// --- WcombT[6144 rows=b*768+j][768 e] = WmodT[row][hd] @ WvB[e][hd] (128² tile)
__global__ __launch_bounds__(256)
void k_comb(const unsigned short* __restrict__ A, const unsigned short* __restrict__ BT,
            unsigned short* __restrict__ OUT)
{
  __shared__ unsigned short As[128 * 32];
  __shared__ unsigned short Bs[128 * 32];
  const int m0 = blockIdx.y * 128;
  const int j0 = blockIdx.x * 128;
  const int t = threadIdx.x;
  const int lane = t & 63;
  const int w = t >> 6, wm = w >> 1, wn = w & 1;

  f32x4 acc[4][4] = {};

  for (int kt = 0; kt < 768; kt += 32){
    if (kt) __syncthreads();
    #pragma unroll
    for (int i = 0; i < 2; i++){
      const char* ga = (const char*)A  + (long)(m0 + i*64 + (t >> 2)) * 1536 + kt*2 + (t & 3) * 16;
      const char* gb = (const char*)BT + (long)(j0 + i*64 + (t >> 2)) * 1536 + kt*2 + (t & 3) * 16;
      char* la = (char*)As + i*4096 + (t & 0xC0) * 16;
      char* lb = (char*)Bs + i*4096 + (t & 0xC0) * 16;
      __builtin_amdgcn_global_load_lds((const __attribute__((address_space(1))) unsigned int*)ga,
                                       (__attribute__((address_space(3))) unsigned int*)la, 16, 0, 0);
      __builtin_amdgcn_global_load_lds((const __attribute__((address_space(1))) unsigned int*)gb,
                                       (__attribute__((address_space(3))) unsigned int*)lb, 16, 0, 0);
    }
    __syncthreads();
    bf16x8 af[4], bfr[4];
    #pragma unroll
    for (int mi = 0; mi < 4; mi++)
      af[mi]  = *(const bf16x8*)&As[(wm*64 + mi*16 + (lane & 15)) * 32 + (lane >> 4) * 8];
    #pragma unroll
    for (int ni = 0; ni < 4; ni++)
      bfr[ni] = *(const bf16x8*)&Bs[(wn*64 + ni*16 + (lane & 15)) * 32 + (lane >> 4) * 8];
    #pragma unroll
    for (int mi = 0; mi < 4; mi++)
      #pragma unroll
      for (int ni = 0; ni < 4; ni++)
        acc[mi][ni] = __builtin_amdgcn_mfma_f32_16x16x32_bf16(af[mi], bfr[ni], acc[mi][ni], 0, 0, 0);
  }

  #pragma unroll
  for (int mi = 0; mi < 4; mi++)
    #pragma unroll
    for (int ni = 0; ni < 4; ni++){
      const int jc = j0 + wn*64 + ni*16 + (lane & 15);
      const long mr = (long)m0 + wm*64 + mi*16 + (lane >> 4) * 4;
      #pragma unroll
      for (int r = 0; r < 4; r++) OUT[(mr + r) * 768 + jc] = f2bf(acc[mi][ni][r]);
    }
}

extern "C" void kernel_launch(void* const* d_in, const int* in_sizes, int n_in,
                              void* d_out, int out_size, void* d_ws, size_t ws_size,
                              hipStream_t stream)
{
  (void)in_sizes; (void)n_in; (void)out_size; (void)ws_size;
  const float* x      = (const float*)d_in[0];
  const float* w_qkv  = (const float*)d_in[1];
  const float* temp   = (const float*)d_in[2];
  const float* w_proj = (const float*)d_in[3];
  const float* b_proj = (const float*)d_in[4];
  float* outF = (float*)d_out;

  char* ws = (char*)d_ws;
  size_t off = 0;
  auto alloc = [&](size_t bytes)->char*{ char* p = ws + off; off += (bytes + 255) & ~(size_t)255; return p; };

  unsigned short* x_bf  = (unsigned short*)alloc(50331648);           // [32768][768] bf16
  unsigned short* WTr   = (unsigned short*)alloc(2359296);            // [1536][768] head-pair layout
  unsigned short* WpT   = (unsigned short*)alloc(1179648);            // [768][768] bf16
  unsigned short* WvB   = (unsigned short*)alloc(1179648);            // [768 e][768 hd] bf16
  float* nrmp           = (float*)alloc(12288L * 64 * 4);             // [12288 rows][64 chunks] f32
  float* Spart          = (float*)alloc(32L * 128 * 2304 * 4);        // [32][128][48][48] f32
  unsigned short* attnT = (unsigned short*)alloc(128L * 48 * 64 * 2); // [128][48 d][64 c] bf16
  unsigned short* WmodT = (unsigned short*)alloc(9437184);            // [8][768 j][768 hd] bf16
  unsigned short* WcombT= (unsigned short*)alloc(9437184);            // [8][768 j][768 e] bf16

  k_cvt<<<12288, 256, 0, stream>>>(x, x_bf, 25165824L);
  k_tconvQK<<<dim3(24, 12), 256, 0, stream>>>(w_qkv, WTr);
  k_tconv<<<dim3(12, 12), 256, 0, stream>>>(w_proj, WpT, 768, 768);
  k_cvtwv<<<288, 256, 0, stream>>>(w_qkv, WvB);
  k_gemmQK<<<2048, 384, 0, stream>>>(x_bf, WTr, Spart, nrmp);
  k_softmax<<<128, 64, 0, stream>>>(Spart, nrmp, temp, attnT);
  k_wmod2<<<dim3(3, 16, 8), 256, 0, stream>>>(WpT, attnT, WmodT);
  k_comb<<<dim3(6, 48), 256, 0, stream>>>(WmodT, WvB, WcombT);
  k_gemmP<<<768, 512, 0, stream>>>(x_bf, WcombT, outF, b_proj);
}